// Round 13
// baseline (150.016 us; speedup 1.0000x reference)
//
#include <hip/hip_runtime.h>
#include <hip/hip_fp16.h>
#include <hip/hip_cooperative_groups.h>
#include <math.h>

namespace cg = cooperative_groups;

// PerVertQuaternion, round 13: single cooperative mega-kernel.
//
// R12 ledger: 4 dispatches, ~41us total vs ~6us traffic floor -> dispatch
// overhead + cross-kernel L2 refetch now dominate. Fuse all phases into one
// hipLaunchCooperativeKernel with grid.sync() between:
//   P1 sort   (block=chunk): LDS histogram + prefix + residue-byte scatter
//             into block-owned S1; Hoff[chunk][bucket]=off|cnt<<16;
//             unstructured faces -> per-chunk lists (never, on this data).
//   P2 transp Hoff -> HoffT (64x64 LDS tiles, coalesced both ways).
//   P3 count  (4 buckets/block-iter, 4x256 subgroups): walk 256 runs,
//             LDS counters, coalesced cntA write.
//   P4 finish (4 row-blocks/block-iter): w for rows base-2..base+255
//             (coalesced contiguous vertex reads; count*w dedup),
//             out[v]=nrm(window sum [+E fixup iff any unstructured]).
//
// Geometry: 256 blocks x 1024 threads -> 1 block/CU guaranteed co-resident
// (LDS 40KB arena, VGPR << 128/wave). All __syncthreads() block-uniform.
//
// Session laws: scattered global WRITES catastrophic (19G sectors/s);
// scattered READS cheap if L2-resident; traffic is not the limit below
// ~50us -- structure, occupancy, and dispatch overhead are.

#define BS     256     // bases per bucket
#define NBMAX  2048    // max buckets (V <= 524288)
#define NCH    256     // sort chunks == grid size
#define CHMAX  4096    // max faces per chunk (F <= 1,048,576)

struct V3 { float x, y, z; };

__device__ __forceinline__ V3 v3sub(const V3& a, const V3& b) {
    return V3{a.x - b.x, a.y - b.y, a.z - b.z};
}
__device__ __forceinline__ V3 v3cross(const V3& a, const V3& b) {
    return V3{a.y * b.z - a.z * b.y,
              a.z * b.x - a.x * b.z,
              a.x * b.y - a.y * b.x};
}
__device__ __forceinline__ float v3dot(const V3& a, const V3& b) {
    return a.x * b.x + a.y * b.y + a.z * b.z;
}
__device__ __forceinline__ V3 v3nrm(const V3& v) {
    float n = sqrtf(v3dot(v, v));
    float inv = 1.0f / fmaxf(n, 1e-12f);
    return V3{v.x * inv, v.y * inv, v.z * inv};
}
__device__ __forceinline__ V3 loadv(const float* __restrict__ p, int i) {
    return V3{p[3 * i], p[3 * i + 1], p[3 * i + 2]};
}

__device__ __forceinline__ void tri2frame(const V3& a, const V3& b, const V3& c,
                                          V3& X, V3& Y, V3& Z) {
    V3 n = v3nrm(v3cross(v3sub(b, a), v3sub(c, a)));
    V3 d = v3sub(b, a);
    X = v3nrm(v3cross(d, n));
    Y = v3nrm(v3cross(d, X));
    Z = v3nrm(d);
}

__device__ __forceinline__ void face_core(V3 ca, V3 cb, V3 cc,
                                          V3 da, V3 db, V3 dc,
                                          float& w0, float& w1, float& w2, float& w3) {
    V3 fn = v3cross(v3sub(cc, cb), v3sub(ca, cb));
    float area = 0.5f * sqrtf(v3dot(fn, fn));

    V3 Xc, Yc, Zc, Xd, Yd, Zd;
    tri2frame(ca, cb, cc, Xc, Yc, Zc);
    tri2frame(da, db, dc, Xd, Yd, Zd);

    // Rot = R_deform * R_cano^T (orthonormal frames -> inv == transpose)
    float Rd[3][3] = {{Xd.x, Yd.x, Zd.x}, {Xd.y, Yd.y, Zd.y}, {Xd.z, Yd.z, Zd.z}};
    float Rc[3][3] = {{Xc.x, Yc.x, Zc.x}, {Xc.y, Yc.y, Zc.y}, {Xc.z, Yc.z, Zc.z}};
    float m00 = Rd[0][0]*Rc[0][0] + Rd[0][1]*Rc[0][1] + Rd[0][2]*Rc[0][2];
    float m01 = Rd[0][0]*Rc[1][0] + Rd[0][1]*Rc[1][1] + Rd[0][2]*Rc[1][2];
    float m02 = Rd[0][0]*Rc[2][0] + Rd[0][1]*Rc[2][1] + Rd[0][2]*Rc[2][2];
    float m10 = Rd[1][0]*Rc[0][0] + Rd[1][1]*Rc[0][1] + Rd[1][2]*Rc[0][2];
    float m11 = Rd[1][0]*Rc[1][0] + Rd[1][1]*Rc[1][1] + Rd[1][2]*Rc[1][2];
    float m12 = Rd[1][0]*Rc[2][0] + Rd[1][1]*Rc[2][1] + Rd[1][2]*Rc[2][2];
    float m20 = Rd[2][0]*Rc[0][0] + Rd[2][1]*Rc[0][1] + Rd[2][2]*Rc[0][2];
    float m21 = Rd[2][0]*Rc[1][0] + Rd[2][1]*Rc[1][1] + Rd[2][2]*Rc[1][2];
    float m22 = Rd[2][0]*Rc[2][0] + Rd[2][1]*Rc[2][1] + Rd[2][2]*Rc[2][2];

    float t0 = 1.0f + m00 + m11 + m22;
    float t1 = 1.0f + m00 - m11 - m22;
    float t2 = 1.0f - m00 + m11 - m22;
    float t3 = 1.0f - m00 - m11 + m22;
    float qa0 = t0 > 0.0f ? sqrtf(t0) : 0.0f;
    float qa1 = t1 > 0.0f ? sqrtf(t1) : 0.0f;
    float qa2 = t2 > 0.0f ? sqrtf(t2) : 0.0f;
    float qa3 = t3 > 0.0f ? sqrtf(t3) : 0.0f;

    int best = 0; float qb = qa0;
    if (qa1 > qb) { best = 1; qb = qa1; }
    if (qa2 > qb) { best = 2; qb = qa2; }
    if (qa3 > qb) { best = 3; qb = qa3; }

    float q0, q1, q2, q3;
    if (best == 0)      { q0 = qa0*qa0; q1 = m21-m12; q2 = m02-m20; q3 = m10-m01; }
    else if (best == 1) { q0 = m21-m12; q1 = qa1*qa1; q2 = m10+m01; q3 = m02+m20; }
    else if (best == 2) { q0 = m02-m20; q1 = m10+m01; q2 = qa2*qa2; q3 = m12+m21; }
    else                { q0 = m10-m01; q1 = m20+m02; q2 = m21+m12; q3 = qa3*qa3; }
    float scale = area / (2.0f * fmaxf(qb, 0.1f));
    w0 = q0 * scale; w1 = q1 * scale; w2 = q2 * scale; w3 = q3 * scale;
}

__device__ __forceinline__ void face_math(const float* __restrict__ mesh,
                                          const float* __restrict__ cano,
                                          int i0, int i1, int i2,
                                          float& w0, float& w1, float& w2, float& w3) {
    face_core(loadv(cano, i0), loadv(cano, i1), loadv(cano, i2),
              loadv(mesh, i0), loadv(mesh, i1), loadv(mesh, i2),
              w0, w1, w2, w3);
}

__device__ __forceinline__ bool is_structured(int i0, int i1, int i2, int V) {
    int e1 = (i0 + 1 < V) ? i0 + 1 : i0 + 1 - V;
    int e2 = (i0 + 2 < V) ? i0 + 2 : i0 + 2 - V;
    return (i1 == e1) & (i2 == e2);
}

// ==================== the fused cooperative kernel ==========================
__global__ __launch_bounds__(1024)
void fused_kernel(const float* __restrict__ mesh,
                  const float* __restrict__ cano,
                  const int* __restrict__ faces,
                  unsigned int* __restrict__ Hoff,    // [NCH][NBMAX]
                  unsigned int* __restrict__ HoffT,   // [NBMAX][NCH]
                  unsigned char* __restrict__ S1,     // [NCH][CHUNKF]
                  int* __restrict__ unstCnt,          // [NCH]
                  int* __restrict__ unstList,         // [NCH][CHUNKF]
                  unsigned int* __restrict__ cntA,    // [V]
                  float* __restrict__ out,
                  int F, int V, int NB, int CHUNKF) {
    cg::grid_group grid = cg::this_grid();
    __shared__ int lds_i[10240];   // 40 KB arena, aliased per phase
    __shared__ int wsum[16];
    __shared__ int unstC;
    __shared__ int anyU;
    int tid = threadIdx.x;

    // ---------------- P1: counting sort (block = chunk) ----------------
    {
        int* h    = lds_i;
        int* off  = lds_i + 2048;
        int* cnt2 = lds_i + 4096;
        int* S0   = lds_i + 6144;   // CHMAX ints

        for (int b = tid; b < NB; b += 1024) { h[b] = 0; cnt2[b] = 0; }
        if (tid == 0) unstC = 0;
        __syncthreads();

        int beg = blockIdx.x * CHUNKF;
        int end = min(F, beg + CHUNKF);

        for (int f = beg + tid; f < end; f += 1024) {
            int i0 = faces[3 * f + 0];
            int i1 = faces[3 * f + 1];
            int i2 = faces[3 * f + 2];
            if (is_structured(i0, i1, i2, V)) {
                S0[f - beg] = i0;
                atomicAdd(&h[i0 >> 8], 1);
            } else {
                S0[f - beg] = -1;
                int p = atomicAdd(&unstC, 1);
                unstList[(size_t)blockIdx.x * CHUNKF + p] = f;
            }
        }
        __syncthreads();

        // exclusive prefix over h[0..NB) -> off[]
        {
            int e0 = (2 * tid < NB)     ? h[2 * tid]     : 0;
            int e1 = (2 * tid + 1 < NB) ? h[2 * tid + 1] : 0;
            int mysum = e0 + e1;
            int lane = tid & 63, wid = tid >> 6;
            int inc = mysum;
            #pragma unroll
            for (int d = 1; d < 64; d <<= 1) {
                int up = __shfl_up(inc, d);
                if (lane >= d) inc += up;
            }
            if (lane == 63) wsum[wid] = inc;
            __syncthreads();
            if (tid == 0) {
                int run = 0;
                #pragma unroll
                for (int i = 0; i < 16; ++i) { int x = wsum[i]; wsum[i] = run; run += x; }
            }
            __syncthreads();
            int excl = wsum[wid] + inc - mysum;
            off[2 * tid]     = excl;
            off[2 * tid + 1] = excl + e0;
        }
        __syncthreads();

        for (int b = tid; b < NB; b += 1024)
            Hoff[(size_t)blockIdx.x * NBMAX + b] =
                (unsigned int)off[b] | ((unsigned int)h[b] << 16);
        if (tid == 0) unstCnt[blockIdx.x] = unstC;

        unsigned char* S1blk = S1 + (size_t)blockIdx.x * CHUNKF;
        for (int j = tid; j < end - beg; j += 1024) {
            int i0 = S0[j];
            if (i0 >= 0) {
                int b = i0 >> 8;
                int p = atomicAdd(&cnt2[b], 1);
                S1blk[off[b] + p] = (unsigned char)(i0 & 0xFF);
            }
        }
    }
    grid.sync();

    // ---------------- P2: transpose Hoff -> HoffT (64x64 tiles) ---------
    {
        unsigned int* tile = (unsigned int*)lds_i;   // 64*65 uints = 16.6 KB
        int tilesB = (NB + 63) >> 6;
        int ntiles = (NCH / 64) * tilesB;
        int tx = tid & 63, ty = tid >> 6;            // ty: 0..15
        for (int t = blockIdx.x; t < ntiles; t += gridDim.x) {
            int cb = (t / tilesB) * 64;   // chunk base
            int bb = (t % tilesB) * 64;   // bucket base
            __syncthreads();
            #pragma unroll
            for (int k = 0; k < 4; ++k) {
                int r = cb + ty + k * 16;  // chunk
                int c = bb + tx;           // bucket
                tile[(ty + k * 16) * 65 + tx] =
                    (c < NB) ? Hoff[(size_t)r * NBMAX + c] : 0u;
            }
            __syncthreads();
            #pragma unroll
            for (int k = 0; k < 4; ++k) {
                int rowT = bb + ty + k * 16;  // bucket
                int colT = cb + tx;           // chunk
                if (rowT < NB)
                    HoffT[(size_t)rowT * NCH + colT] = tile[tx * 65 + ty + k * 16];
            }
        }
    }
    grid.sync();

    // ---------------- P3: count (4 buckets per block-iteration) ---------
    {
        unsigned int* cnt_l = (unsigned int*)lds_i;  // [4][256]
        int k = tid >> 8, r = tid & 255;
        for (int g = blockIdx.x * 4; g < NB; g += gridDim.x * 4) {
            int b = g + k;
            cnt_l[k * 256 + r] = 0;
            __syncthreads();
            if (b < NB) {
                unsigned int pc = HoffT[(size_t)b * NCH + r];
                int start = (int)(pc & 0xFFFFu);
                int cnt   = (int)(pc >> 16);
                const unsigned char* run = S1 + (size_t)r * CHUNKF + start;
                for (int j = 0; j < cnt; ++j)
                    atomicAdd(&cnt_l[k * 256 + run[j]], 1u);
            }
            __syncthreads();
            if (b < NB) {
                int row = b * BS + r;
                if (row < V) cntA[row] = cnt_l[k * 256 + r];
            }
            __syncthreads();
        }
    }
    grid.sync();

    // ---------------- P4: finish (4 row-blocks per block-iteration) -----
    {
        float4* TwA = (float4*)lds_i;            // [4][260] = 16.6 KB
        float4* EwA = TwA + 4 * 260;             // [4][256] = 16 KB (anyU only)
        if (tid == 0) anyU = 0;
        __syncthreads();
        if (tid < NCH) { if (unstCnt[tid]) atomicOr(&anyU, 1); }
        __syncthreads();

        int k = tid >> 8, r = tid & 255;
        float4* Tw = TwA + k * 260;
        float4* Ew = EwA + k * 256;

        for (int g = blockIdx.x * 4; g < NB; g += gridDim.x * 4) {
            int rb = g + k;
            int base = rb * BS;
            __syncthreads();
            if (rb < NB) {
                for (int j = r; j < BS + 2; j += 256) {
                    int row = base - 2 + j;
                    if (row < 0) row += V;
                    if (row >= V) row -= V;
                    unsigned int c = cntA[row];
                    float4 res = make_float4(0.f, 0.f, 0.f, 0.f);
                    if (c > 0) {
                        int i1 = (row + 1 < V) ? row + 1 : row + 1 - V;
                        int i2 = (row + 2 < V) ? row + 2 : row + 2 - V;
                        float w0, w1, w2, w3;
                        face_math(mesh, cano, row, i1, i2, w0, w1, w2, w3);
                        float fc = (float)c;
                        res = make_float4(w0 * fc, w1 * fc, w2 * fc, w3 * fc);
                    }
                    Tw[j] = res;
                }
            }
            if (anyU) {   // rare/never: unstructured fixup via LDS
                if (rb < NB) Ew[r] = make_float4(0.f, 0.f, 0.f, 0.f);
                __syncthreads();
                for (int blk = 0; blk < NCH; ++blk) {
                    int cnt = unstCnt[blk];
                    for (int j = r; j < cnt; j += 256) {
                        if (rb < NB) {
                            int f = unstList[(size_t)blk * CHUNKF + j];
                            int i0 = faces[3*f+0], i1 = faces[3*f+1], i2 = faces[3*f+2];
                            float w0, w1, w2, w3;
                            face_math(mesh, cano, i0, i1, i2, w0, w1, w2, w3);
                            int tg[3] = {i0, i1, i2};
                            #pragma unroll
                            for (int kk = 0; kk < 3; ++kk) {
                                int v = tg[kk];
                                if (v >= base && v < base + BS && v < V) {
                                    float* e = (float*)&Ew[v - base];
                                    atomicAdd(e + 0, w0);
                                    atomicAdd(e + 1, w1);
                                    atomicAdd(e + 2, w2);
                                    atomicAdd(e + 3, w3);
                                }
                            }
                        }
                    }
                }
            }
            __syncthreads();
            if (rb < NB) {
                int v = base + r;
                if (v < V) {
                    float4 a = Tw[r + 2], b4 = Tw[r + 1], c4 = Tw[r];
                    float ex = 0.f, ey = 0.f, ez = 0.f, ew = 0.f;
                    if (anyU) { float4 e = Ew[r]; ex = e.x; ey = e.y; ez = e.z; ew = e.w; }
                    float x = a.x + b4.x + c4.x + ex;
                    float y = a.y + b4.y + c4.y + ey;
                    float z = a.z + b4.z + c4.z + ez;
                    float w = a.w + b4.w + c4.w + ew;
                    float n = sqrtf(x * x + y * y + z * z + w * w);
                    float inv = 1.0f / fmaxf(n, 1e-6f);
                    reinterpret_cast<float4*>(out)[v] =
                        make_float4(x * inv, y * inv, z * inv, w * inv);
                }
            }
            __syncthreads();
        }
    }
}

// ================= fallback paths (proven R4 / R1) ==========================
typedef _Float16 hf2 __attribute__((ext_vector_type(2)));

__device__ __forceinline__ void atomic_pk_add_f16(__half* base, float a, float b) {
#if __has_builtin(__builtin_amdgcn_global_atomic_fadd_v2f16)
    hf2 v; v.x = (_Float16)a; v.y = (_Float16)b;
    __builtin_amdgcn_global_atomic_fadd_v2f16(
        (__attribute__((address_space(1))) hf2*)base, v);
#else
    union { _Float16 h[2]; unsigned int u; } pk;
    pk.h[0] = (_Float16)a; pk.h[1] = (_Float16)b;
    asm volatile("global_atomic_pk_add_f16 %0, %1, off"
                 :: "v"(base), "v"(pk.u) : "memory");
#endif
}

__global__ void face_kernel_f16(const float* __restrict__ mesh,
                                const float* __restrict__ cano,
                                const int* __restrict__ faces,
                                __half* __restrict__ T, float* __restrict__ E,
                                int F, int V) {
    int f = blockIdx.x * blockDim.x + threadIdx.x;
    if (f >= F) return;
    int i0 = faces[3*f+0], i1 = faces[3*f+1], i2 = faces[3*f+2];
    float w0, w1, w2, w3;
    face_math(mesh, cano, i0, i1, i2, w0, w1, w2, w3);
    if (is_structured(i0, i1, i2, V)) {
        __half* t = T + 4 * (size_t)i0;
        atomic_pk_add_f16(t,     w0, w1);
        atomic_pk_add_f16(t + 2, w2, w3);
    } else {
        atomicAdd(&E[4*i0+0], w0); atomicAdd(&E[4*i0+1], w1);
        atomicAdd(&E[4*i0+2], w2); atomicAdd(&E[4*i0+3], w3);
        atomicAdd(&E[4*i1+0], w0); atomicAdd(&E[4*i1+1], w1);
        atomicAdd(&E[4*i1+2], w2); atomicAdd(&E[4*i1+3], w3);
        atomicAdd(&E[4*i2+0], w0); atomicAdd(&E[4*i2+1], w1);
        atomicAdd(&E[4*i2+2], w2); atomicAdd(&E[4*i2+3], w3);
    }
}

__global__ void finish_kernel_f16(const __half* __restrict__ T,
                                  const float* __restrict__ E,
                                  float* __restrict__ out, int V) {
    int v = blockIdx.x * blockDim.x + threadIdx.x;
    if (v >= V) return;
    int vm1 = (v >= 1) ? v - 1 : v - 1 + V;
    int vm2 = (v >= 2) ? v - 2 : v - 2 + V;
    const __half2* p0 = reinterpret_cast<const __half2*>(T + 4 * (size_t)v);
    const __half2* p1 = reinterpret_cast<const __half2*>(T + 4 * (size_t)vm1);
    const __half2* p2 = reinterpret_cast<const __half2*>(T + 4 * (size_t)vm2);
    float2 a01 = __half22float2(p0[0]), a23 = __half22float2(p0[1]);
    float2 b01 = __half22float2(p1[0]), b23 = __half22float2(p1[1]);
    float2 c01 = __half22float2(p2[0]), c23 = __half22float2(p2[1]);
    float4 e = reinterpret_cast<const float4*>(E)[v];
    float x = a01.x + b01.x + c01.x + e.x;
    float y = a01.y + b01.y + c01.y + e.y;
    float z = a23.x + b23.x + c23.x + e.z;
    float w = a23.y + b23.y + c23.y + e.w;
    float n = sqrtf(x * x + y * y + z * z + w * w);
    float inv = 1.0f / fmaxf(n, 1e-6f);
    reinterpret_cast<float4*>(out)[v] = make_float4(x * inv, y * inv, z * inv, w * inv);
}

__global__ void face_kernel_direct(const float* __restrict__ mesh,
                                   const float* __restrict__ cano,
                                   const int* __restrict__ faces,
                                   float* __restrict__ out, int F) {
    int f = blockIdx.x * blockDim.x + threadIdx.x;
    if (f >= F) return;
    int i0 = faces[3*f+0], i1 = faces[3*f+1], i2 = faces[3*f+2];
    float w0, w1, w2, w3;
    face_math(mesh, cano, i0, i1, i2, w0, w1, w2, w3);
    atomicAdd(&out[4*i0+0], w0); atomicAdd(&out[4*i0+1], w1);
    atomicAdd(&out[4*i0+2], w2); atomicAdd(&out[4*i0+3], w3);
    atomicAdd(&out[4*i1+0], w0); atomicAdd(&out[4*i1+1], w1);
    atomicAdd(&out[4*i1+2], w2); atomicAdd(&out[4*i1+3], w3);
    atomicAdd(&out[4*i2+0], w0); atomicAdd(&out[4*i2+1], w1);
    atomicAdd(&out[4*i2+2], w2); atomicAdd(&out[4*i2+3], w3);
}

__global__ void norm_kernel(float* __restrict__ out, int V) {
    int v = blockIdx.x * blockDim.x + threadIdx.x;
    if (v >= V) return;
    float4 q = reinterpret_cast<float4*>(out)[v];
    float n = sqrtf(q.x*q.x + q.y*q.y + q.z*q.z + q.w*q.w);
    float inv = 1.0f / fmaxf(n, 1e-6f);
    reinterpret_cast<float4*>(out)[v] = make_float4(q.x*inv, q.y*inv, q.z*inv, q.w*inv);
}

extern "C" void kernel_launch(void* const* d_in, const int* in_sizes, int n_in,
                              void* d_out, int out_size, void* d_ws, size_t ws_size,
                              hipStream_t stream) {
    const float* mesh  = (const float*)d_in[0];
    const float* cano  = (const float*)d_in[1];
    const int*   faces = (const int*)d_in[2];
    float* out = (float*)d_out;

    int V = in_sizes[0] / 3;
    int F = in_sizes[2] / 3;
    const int TB = 256;
    int NB = (V + BS - 1) / BS;
    int CHUNKF = (F + NCH - 1) / NCH;

    // ws layout (byte offsets)
    size_t bHoff  = (size_t)NCH * NBMAX * 4;                  // 2 MB
    size_t bHoffT = (size_t)NBMAX * NCH * 4;                  // 2 MB
    size_t bS1    = (((size_t)NCH * CHUNKF) + 15) & ~15ull;   // ~1 MB
    size_t bCnt   = (size_t)V * 4;                            // 2 MB
    size_t bUC    = (size_t)NCH * 4;                          // 1 KB
    size_t bUL    = (size_t)NCH * CHUNKF * 4;                 // 4 MB
    size_t needFull = bHoff + bHoffT + bS1 + bCnt + bUC + bUL;

    size_t bytesTf16 = (size_t)V * 4 * sizeof(__half);
    size_t bytesEf32 = (size_t)V * 4 * sizeof(float);

    int coop = 0;
    int dev = 0;
    (void)hipGetDevice(&dev);
    (void)hipDeviceGetAttribute(&coop, hipDeviceAttributeCooperativeLaunch, dev);

    if (coop && ws_size >= needFull && NB <= NBMAX && CHUNKF <= CHMAX) {
        char* p = (char*)d_ws;
        unsigned int*  Hoff    = (unsigned int*)p;   p += bHoff;
        unsigned int*  HoffT   = (unsigned int*)p;   p += bHoffT;
        unsigned char* S1      = (unsigned char*)p;  p += bS1;
        unsigned int*  cntA    = (unsigned int*)p;   p += bCnt;
        int*           unstCnt = (int*)p;            p += bUC;
        int*           unstList = (int*)p;

        void* args[] = {
            (void*)&mesh, (void*)&cano, (void*)&faces,
            (void*)&Hoff, (void*)&HoffT, (void*)&S1,
            (void*)&unstCnt, (void*)&unstList, (void*)&cntA,
            (void*)&out, (void*)&F, (void*)&V, (void*)&NB, (void*)&CHUNKF
        };
        (void)hipLaunchCooperativeKernel((void*)fused_kernel,
                                         dim3(NCH), dim3(1024), args, 0, stream);
    } else if (ws_size >= bytesTf16 + bytesEf32) {
        __half* T = (__half*)d_ws;
        float*  E = (float*)((char*)d_ws + bytesTf16);
        (void)hipMemsetAsync(d_ws, 0, bytesTf16 + bytesEf32, stream);
        face_kernel_f16<<<(F + TB - 1) / TB, TB, 0, stream>>>(mesh, cano, faces, T, E, F, V);
        finish_kernel_f16<<<(V + TB - 1) / TB, TB, 0, stream>>>(T, E, out, V);
    } else {
        (void)hipMemsetAsync(out, 0, (size_t)V * 4 * sizeof(float), stream);
        face_kernel_direct<<<(F + TB - 1) / TB, TB, 0, stream>>>(mesh, cano, faces, out, F);
        norm_kernel<<<(V + TB - 1) / TB, TB, 0, stream>>>(out, V);
    }
}

// Round 14
// 46.122 us; speedup vs baseline: 3.2526x; 3.2526x over previous
//
#include <hip/hip_runtime.h>
#include <hip/hip_fp16.h>
#include <math.h>

// PerVertQuaternion, round 14: 2-dispatch pipeline (sort -> countfinish).
//
// R13 lesson (new session law): grid.sync() on MI355X costs ~30us each
// (cross-XCD L2 flush + barrier) -- kernel-boundary sync is CHEAPER than
// cooperative sync. Reverted to R12's multi-kernel shape, then cut
// 4 dispatches -> 2 by making the count+finish phase fully block-local:
// block b walks bucket b's runs (counts for its 256 rows) AND bucket b-1's
// runs (filtered for the 2 boundary residues), then does the dedup'd
// per-row face math (count*w) and writes out directly. No HoffT, no cntA.
//
// Session laws: scattered global WRITES catastrophic (19G sectors/s,
// cross-XCD write-through); scattered global READS cheap when L2/L3
// resident (line amplification prices at L2 BW, not HBM); rocclr memset
// slow; grid.sync ~30us; dedup by base vertex (faces sharing i0 are
// identical -> only count[i0] needed).

#define BS     256     // bases per bucket
#define NBMAX  2048    // max buckets (V <= 524288)
#define NCH    512     // sort chunks
#define CHMAX  2048    // max faces per chunk (F <= 1,048,576)

struct V3 { float x, y, z; };

__device__ __forceinline__ V3 v3sub(const V3& a, const V3& b) {
    return V3{a.x - b.x, a.y - b.y, a.z - b.z};
}
__device__ __forceinline__ V3 v3cross(const V3& a, const V3& b) {
    return V3{a.y * b.z - a.z * b.y,
              a.z * b.x - a.x * b.z,
              a.x * b.y - a.y * b.x};
}
__device__ __forceinline__ float v3dot(const V3& a, const V3& b) {
    return a.x * b.x + a.y * b.y + a.z * b.z;
}
__device__ __forceinline__ V3 v3nrm(const V3& v) {
    float n = sqrtf(v3dot(v, v));
    float inv = 1.0f / fmaxf(n, 1e-12f);
    return V3{v.x * inv, v.y * inv, v.z * inv};
}
__device__ __forceinline__ V3 loadv(const float* __restrict__ p, int i) {
    return V3{p[3 * i], p[3 * i + 1], p[3 * i + 2]};
}

__device__ __forceinline__ void tri2frame(const V3& a, const V3& b, const V3& c,
                                          V3& X, V3& Y, V3& Z) {
    V3 n = v3nrm(v3cross(v3sub(b, a), v3sub(c, a)));
    V3 d = v3sub(b, a);
    X = v3nrm(v3cross(d, n));
    Y = v3nrm(v3cross(d, X));
    Z = v3nrm(d);
}

__device__ __forceinline__ void face_core(V3 ca, V3 cb, V3 cc,
                                          V3 da, V3 db, V3 dc,
                                          float& w0, float& w1, float& w2, float& w3) {
    V3 fn = v3cross(v3sub(cc, cb), v3sub(ca, cb));
    float area = 0.5f * sqrtf(v3dot(fn, fn));

    V3 Xc, Yc, Zc, Xd, Yd, Zd;
    tri2frame(ca, cb, cc, Xc, Yc, Zc);
    tri2frame(da, db, dc, Xd, Yd, Zd);

    // Rot = R_deform * R_cano^T (orthonormal frames -> inv == transpose)
    float Rd[3][3] = {{Xd.x, Yd.x, Zd.x}, {Xd.y, Yd.y, Zd.y}, {Xd.z, Yd.z, Zd.z}};
    float Rc[3][3] = {{Xc.x, Yc.x, Zc.x}, {Xc.y, Yc.y, Zc.y}, {Xc.z, Yc.z, Zc.z}};
    float m00 = Rd[0][0]*Rc[0][0] + Rd[0][1]*Rc[0][1] + Rd[0][2]*Rc[0][2];
    float m01 = Rd[0][0]*Rc[1][0] + Rd[0][1]*Rc[1][1] + Rd[0][2]*Rc[1][2];
    float m02 = Rd[0][0]*Rc[2][0] + Rd[0][1]*Rc[2][1] + Rd[0][2]*Rc[2][2];
    float m10 = Rd[1][0]*Rc[0][0] + Rd[1][1]*Rc[0][1] + Rd[1][2]*Rc[0][2];
    float m11 = Rd[1][0]*Rc[1][0] + Rd[1][1]*Rc[1][1] + Rd[1][2]*Rc[1][2];
    float m12 = Rd[1][0]*Rc[2][0] + Rd[1][1]*Rc[2][1] + Rd[1][2]*Rc[2][2];
    float m20 = Rd[2][0]*Rc[0][0] + Rd[2][1]*Rc[0][1] + Rd[2][2]*Rc[0][2];
    float m21 = Rd[2][0]*Rc[1][0] + Rd[2][1]*Rc[1][1] + Rd[2][2]*Rc[1][2];
    float m22 = Rd[2][0]*Rc[2][0] + Rd[2][1]*Rc[2][1] + Rd[2][2]*Rc[2][2];

    float t0 = 1.0f + m00 + m11 + m22;
    float t1 = 1.0f + m00 - m11 - m22;
    float t2 = 1.0f - m00 + m11 - m22;
    float t3 = 1.0f - m00 - m11 + m22;
    float qa0 = t0 > 0.0f ? sqrtf(t0) : 0.0f;
    float qa1 = t1 > 0.0f ? sqrtf(t1) : 0.0f;
    float qa2 = t2 > 0.0f ? sqrtf(t2) : 0.0f;
    float qa3 = t3 > 0.0f ? sqrtf(t3) : 0.0f;

    int best = 0; float qb = qa0;
    if (qa1 > qb) { best = 1; qb = qa1; }
    if (qa2 > qb) { best = 2; qb = qa2; }
    if (qa3 > qb) { best = 3; qb = qa3; }

    float q0, q1, q2, q3;
    if (best == 0)      { q0 = qa0*qa0; q1 = m21-m12; q2 = m02-m20; q3 = m10-m01; }
    else if (best == 1) { q0 = m21-m12; q1 = qa1*qa1; q2 = m10+m01; q3 = m02+m20; }
    else if (best == 2) { q0 = m02-m20; q1 = m10+m01; q2 = qa2*qa2; q3 = m12+m21; }
    else                { q0 = m10-m01; q1 = m20+m02; q2 = m21+m12; q3 = qa3*qa3; }
    float scale = area / (2.0f * fmaxf(qb, 0.1f));
    w0 = q0 * scale; w1 = q1 * scale; w2 = q2 * scale; w3 = q3 * scale;
}

__device__ __forceinline__ void face_math(const float* __restrict__ mesh,
                                          const float* __restrict__ cano,
                                          int i0, int i1, int i2,
                                          float& w0, float& w1, float& w2, float& w3) {
    face_core(loadv(cano, i0), loadv(cano, i1), loadv(cano, i2),
              loadv(mesh, i0), loadv(mesh, i1), loadv(mesh, i2),
              w0, w1, w2, w3);
}

__device__ __forceinline__ bool is_structured(int i0, int i1, int i2, int V) {
    int e1 = (i0 + 1 < V) ? i0 + 1 : i0 + 1 - V;
    int e2 = (i0 + 2 < V) ? i0 + 2 : i0 + 2 - V;
    return (i1 == e1) & (i2 == e2);
}

// ---------------- P1: counting sort -> residue bytes, block-major -----------
__global__ __launch_bounds__(1024)
void sort_kernel(const int* __restrict__ faces,
                 unsigned int* __restrict__ Hoff,      // [NCH][NBMAX] off|cnt<<16
                 unsigned char* __restrict__ S1,       // [NCH][CHUNKF] residues
                 int* __restrict__ unstCnt,            // [NCH]
                 int* __restrict__ unstList,           // [NCH][CHUNKF] face idx
                 int F, int V, int NB, int CHUNKF) {
    __shared__ int h[NBMAX];
    __shared__ int off[NBMAX];
    __shared__ int cnt2[NBMAX];
    __shared__ int S0[CHMAX];
    __shared__ int wsum[16];
    __shared__ int unstC;

    int tid = threadIdx.x;
    for (int b = tid; b < NB; b += 1024) { h[b] = 0; cnt2[b] = 0; }
    if (tid == 0) unstC = 0;
    __syncthreads();

    int beg = blockIdx.x * CHUNKF;
    int end = min(F, beg + CHUNKF);

    // pass A: histogram + cache i0 in LDS; unstructured -> per-chunk list
    for (int f = beg + tid; f < end; f += 1024) {
        int i0 = faces[3 * f + 0];
        int i1 = faces[3 * f + 1];
        int i2 = faces[3 * f + 2];
        if (is_structured(i0, i1, i2, V)) {
            S0[f - beg] = i0;
            atomicAdd(&h[i0 >> 8], 1);
        } else {
            S0[f - beg] = -1;
            int p = atomicAdd(&unstC, 1);
            unstList[(size_t)blockIdx.x * CHUNKF + p] = f;
        }
    }
    __syncthreads();

    // exclusive prefix over h[0..NB) -> off[]
    {
        int e0 = (2 * tid < NB)     ? h[2 * tid]     : 0;
        int e1 = (2 * tid + 1 < NB) ? h[2 * tid + 1] : 0;
        int mysum = e0 + e1;
        int lane = tid & 63, wid = tid >> 6;
        int inc = mysum;
        #pragma unroll
        for (int d = 1; d < 64; d <<= 1) {
            int up = __shfl_up(inc, d);
            if (lane >= d) inc += up;
        }
        if (lane == 63) wsum[wid] = inc;
        __syncthreads();
        if (tid == 0) {
            int run = 0;
            #pragma unroll
            for (int i = 0; i < 16; ++i) { int x = wsum[i]; wsum[i] = run; run += x; }
        }
        __syncthreads();
        int excl = wsum[wid] + inc - mysum;
        if (2 * tid < NBMAX)     off[2 * tid]     = excl;
        if (2 * tid + 1 < NBMAX) off[2 * tid + 1] = excl + e0;
    }
    __syncthreads();

    // publish run descriptors (coalesced) + unstructured count
    for (int b = tid; b < NB; b += 1024)
        Hoff[(size_t)blockIdx.x * NBMAX + b] =
            (unsigned int)off[b] | ((unsigned int)h[b] << 16);
    if (tid == 0) unstCnt[blockIdx.x] = unstC;

    // pass B: residue bytes into block-owned chunk (XCD-local scatter)
    unsigned char* S1blk = S1 + (size_t)blockIdx.x * CHUNKF;
    for (int j = tid; j < end - beg; j += 1024) {
        int i0 = S0[j];
        if (i0 >= 0) {
            int b = i0 >> 8;
            int p = atomicAdd(&cnt2[b], 1);
            S1blk[off[b] + p] = (unsigned char)(i0 & 0xFF);
        }
    }
}

// ---------------- P2: fused count + math + window-sum + normalize -----------
// Block b: counts bucket b's residues (rows base..base+255) and the two
// boundary rows (base-1, base-2, from neighbor bucket(s)), then per-row
// dedup'd face math and the shifted-window normalize -- all block-local.
__global__ __launch_bounds__(256)
void countfinish_kernel(const float* __restrict__ mesh,
                        const float* __restrict__ cano,
                        const unsigned int* __restrict__ Hoff,
                        const unsigned char* __restrict__ S1,
                        const int* __restrict__ unstCnt,
                        const int* __restrict__ unstList,
                        const int* __restrict__ faces,
                        float* __restrict__ out,
                        int V, int NB, int CHUNKF) {
    __shared__ unsigned int cnt_l[BS];
    __shared__ unsigned int cntB[2];      // counts for rows base-2, base-1
    __shared__ float4 Tw[BS + 2];
    __shared__ float Ew[BS][4];
    __shared__ int anyU;

    int b = blockIdx.x;
    int base = b * BS;
    int t = threadIdx.x;

    cnt_l[t] = 0;
    if (t < 2) cntB[t] = 0;
    if (t == 0) anyU = 0;
    __syncthreads();
    {   // any unstructured faces anywhere? (512 ints, L2-broadcast)
        int u = unstCnt[t] | unstCnt[t + 256];
        if (u) atomicOr(&anyU, 1);
    }

    // walk bucket b's runs across all chunks (2 runs per thread)
    for (int r = t; r < NCH; r += 256) {
        unsigned int pc = Hoff[(size_t)r * NBMAX + b];
        int start = (int)(pc & 0xFFFFu);
        int cnt   = (int)(pc >> 16);
        const unsigned char* run = S1 + (size_t)r * CHUNKF + start;
        for (int j = 0; j < cnt; ++j)
            atomicAdd(&cnt_l[run[j]], 1u);
    }

    // boundary rows base-2 (k=0), base-1 (k=1): walk their bucket's runs
    int row0 = base - 2; if (row0 < 0) row0 += V;
    int row1 = base - 1; if (row1 < 0) row1 += V;
    int bb0 = row0 >> 8, bb1 = row1 >> 8;
    unsigned char res0 = (unsigned char)(row0 & 255);
    unsigned char res1 = (unsigned char)(row1 & 255);
    for (int r = t; r < NCH; r += 256) {
        unsigned int pc = Hoff[(size_t)r * NBMAX + bb0];
        int start = (int)(pc & 0xFFFFu);
        int cnt   = (int)(pc >> 16);
        const unsigned char* run = S1 + (size_t)r * CHUNKF + start;
        for (int j = 0; j < cnt; ++j) {
            unsigned char x = run[j];
            if (x == res0) atomicAdd(&cntB[0], 1u);
            if (bb1 == bb0 && x == res1) atomicAdd(&cntB[1], 1u);
        }
    }
    if (bb1 != bb0) {   // only when V % 256 puts the two rows in diff buckets
        for (int r = t; r < NCH; r += 256) {
            unsigned int pc = Hoff[(size_t)r * NBMAX + bb1];
            int start = (int)(pc & 0xFFFFu);
            int cnt   = (int)(pc >> 16);
            const unsigned char* run = S1 + (size_t)r * CHUNKF + start;
            for (int j = 0; j < cnt; ++j)
                if (run[j] == res1) atomicAdd(&cntB[1], 1u);
        }
    }
    __syncthreads();

    // per-row dedup'd math: Tw[j] = count * w for row base-2+j
    int rows = min(BS, V - base);
    for (int j = t; j < rows + 2; j += 256) {
        int row = base - 2 + j;
        if (row < 0) row += V;
        unsigned int c = (j == 0) ? cntB[0] : (j == 1) ? cntB[1] : cnt_l[j - 2];
        float4 res = make_float4(0.f, 0.f, 0.f, 0.f);
        if (c > 0) {
            int i1 = (row + 1 < V) ? row + 1 : row + 1 - V;
            int i2 = (row + 2 < V) ? row + 2 : row + 2 - V;
            float w0, w1, w2, w3;
            face_math(mesh, cano, row, i1, i2, w0, w1, w2, w3);
            float fc = (float)c;
            res = make_float4(w0 * fc, w1 * fc, w2 * fc, w3 * fc);
        }
        Tw[j] = res;
    }
    __syncthreads();

    if (anyU) {   // rare/never path: unstructured fixup via LDS
        Ew[t][0] = Ew[t][1] = Ew[t][2] = Ew[t][3] = 0.f;
        __syncthreads();
        for (int blk = 0; blk < NCH; ++blk) {
            int cnt = unstCnt[blk];
            for (int j = t; j < cnt; j += 256) {
                int f = unstList[(size_t)blk * CHUNKF + j];
                int i0 = faces[3*f+0], i1 = faces[3*f+1], i2 = faces[3*f+2];
                float w0, w1, w2, w3;
                face_math(mesh, cano, i0, i1, i2, w0, w1, w2, w3);
                int tg[3] = {i0, i1, i2};
                #pragma unroll
                for (int k = 0; k < 3; ++k) {
                    int v = tg[k];
                    if (v >= base && v < base + BS && v < V) {
                        atomicAdd(&Ew[v - base][0], w0);
                        atomicAdd(&Ew[v - base][1], w1);
                        atomicAdd(&Ew[v - base][2], w2);
                        atomicAdd(&Ew[v - base][3], w3);
                    }
                }
            }
        }
        __syncthreads();
    }

    int v = base + t;
    if (t < rows) {
        float4 a4 = Tw[t + 2], b4 = Tw[t + 1], c4 = Tw[t];
        float ex = 0.f, ey = 0.f, ez = 0.f, ew = 0.f;
        if (anyU) { ex = Ew[t][0]; ey = Ew[t][1]; ez = Ew[t][2]; ew = Ew[t][3]; }
        float x = a4.x + b4.x + c4.x + ex;
        float y = a4.y + b4.y + c4.y + ey;
        float z = a4.z + b4.z + c4.z + ez;
        float w = a4.w + b4.w + c4.w + ew;
        float n = sqrtf(x * x + y * y + z * z + w * w);
        float inv = 1.0f / fmaxf(n, 1e-6f);
        reinterpret_cast<float4*>(out)[v] = make_float4(x * inv, y * inv, z * inv, w * inv);
    }
}

// ================= fallback paths (proven R4 / R1) ==========================
typedef _Float16 hf2 __attribute__((ext_vector_type(2)));

__device__ __forceinline__ void atomic_pk_add_f16(__half* base, float a, float b) {
#if __has_builtin(__builtin_amdgcn_global_atomic_fadd_v2f16)
    hf2 v; v.x = (_Float16)a; v.y = (_Float16)b;
    __builtin_amdgcn_global_atomic_fadd_v2f16(
        (__attribute__((address_space(1))) hf2*)base, v);
#else
    union { _Float16 h[2]; unsigned int u; } pk;
    pk.h[0] = (_Float16)a; pk.h[1] = (_Float16)b;
    asm volatile("global_atomic_pk_add_f16 %0, %1, off"
                 :: "v"(base), "v"(pk.u) : "memory");
#endif
}

__global__ void face_kernel_f16(const float* __restrict__ mesh,
                                const float* __restrict__ cano,
                                const int* __restrict__ faces,
                                __half* __restrict__ T, float* __restrict__ E,
                                int F, int V) {
    int f = blockIdx.x * blockDim.x + threadIdx.x;
    if (f >= F) return;
    int i0 = faces[3*f+0], i1 = faces[3*f+1], i2 = faces[3*f+2];
    float w0, w1, w2, w3;
    face_math(mesh, cano, i0, i1, i2, w0, w1, w2, w3);
    if (is_structured(i0, i1, i2, V)) {
        __half* t = T + 4 * (size_t)i0;
        atomic_pk_add_f16(t,     w0, w1);
        atomic_pk_add_f16(t + 2, w2, w3);
    } else {
        atomicAdd(&E[4*i0+0], w0); atomicAdd(&E[4*i0+1], w1);
        atomicAdd(&E[4*i0+2], w2); atomicAdd(&E[4*i0+3], w3);
        atomicAdd(&E[4*i1+0], w0); atomicAdd(&E[4*i1+1], w1);
        atomicAdd(&E[4*i1+2], w2); atomicAdd(&E[4*i1+3], w3);
        atomicAdd(&E[4*i2+0], w0); atomicAdd(&E[4*i2+1], w1);
        atomicAdd(&E[4*i2+2], w2); atomicAdd(&E[4*i2+3], w3);
    }
}

__global__ void finish_kernel_f16(const __half* __restrict__ T,
                                  const float* __restrict__ E,
                                  float* __restrict__ out, int V) {
    int v = blockIdx.x * blockDim.x + threadIdx.x;
    if (v >= V) return;
    int vm1 = (v >= 1) ? v - 1 : v - 1 + V;
    int vm2 = (v >= 2) ? v - 2 : v - 2 + V;
    const __half2* p0 = reinterpret_cast<const __half2*>(T + 4 * (size_t)v);
    const __half2* p1 = reinterpret_cast<const __half2*>(T + 4 * (size_t)vm1);
    const __half2* p2 = reinterpret_cast<const __half2*>(T + 4 * (size_t)vm2);
    float2 a01 = __half22float2(p0[0]), a23 = __half22float2(p0[1]);
    float2 b01 = __half22float2(p1[0]), b23 = __half22float2(p1[1]);
    float2 c01 = __half22float2(p2[0]), c23 = __half22float2(p2[1]);
    float4 e = reinterpret_cast<const float4*>(E)[v];
    float x = a01.x + b01.x + c01.x + e.x;
    float y = a01.y + b01.y + c01.y + e.y;
    float z = a23.x + b23.x + c23.x + e.z;
    float w = a23.y + b23.y + c23.y + e.w;
    float n = sqrtf(x * x + y * y + z * z + w * w);
    float inv = 1.0f / fmaxf(n, 1e-6f);
    reinterpret_cast<float4*>(out)[v] = make_float4(x * inv, y * inv, z * inv, w * inv);
}

__global__ void face_kernel_direct(const float* __restrict__ mesh,
                                   const float* __restrict__ cano,
                                   const int* __restrict__ faces,
                                   float* __restrict__ out, int F) {
    int f = blockIdx.x * blockDim.x + threadIdx.x;
    if (f >= F) return;
    int i0 = faces[3*f+0], i1 = faces[3*f+1], i2 = faces[3*f+2];
    float w0, w1, w2, w3;
    face_math(mesh, cano, i0, i1, i2, w0, w1, w2, w3);
    atomicAdd(&out[4*i0+0], w0); atomicAdd(&out[4*i0+1], w1);
    atomicAdd(&out[4*i0+2], w2); atomicAdd(&out[4*i0+3], w3);
    atomicAdd(&out[4*i1+0], w0); atomicAdd(&out[4*i1+1], w1);
    atomicAdd(&out[4*i1+2], w2); atomicAdd(&out[4*i1+3], w3);
    atomicAdd(&out[4*i2+0], w0); atomicAdd(&out[4*i2+1], w1);
    atomicAdd(&out[4*i2+2], w2); atomicAdd(&out[4*i2+3], w3);
}

__global__ void norm_kernel(float* __restrict__ out, int V) {
    int v = blockIdx.x * blockDim.x + threadIdx.x;
    if (v >= V) return;
    float4 q = reinterpret_cast<float4*>(out)[v];
    float n = sqrtf(q.x*q.x + q.y*q.y + q.z*q.z + q.w*q.w);
    float inv = 1.0f / fmaxf(n, 1e-6f);
    reinterpret_cast<float4*>(out)[v] = make_float4(q.x*inv, q.y*inv, q.z*inv, q.w*inv);
}

extern "C" void kernel_launch(void* const* d_in, const int* in_sizes, int n_in,
                              void* d_out, int out_size, void* d_ws, size_t ws_size,
                              hipStream_t stream) {
    const float* mesh  = (const float*)d_in[0];
    const float* cano  = (const float*)d_in[1];
    const int*   faces = (const int*)d_in[2];
    float* out = (float*)d_out;

    int V = in_sizes[0] / 3;
    int F = in_sizes[2] / 3;
    const int TB = 256;
    int NB = (V + BS - 1) / BS;
    int CHUNKF = (F + NCH - 1) / NCH;

    // ws layout (byte offsets)
    size_t bHoff = (size_t)NCH * NBMAX * 4;                  // 4 MB
    size_t bS1   = (((size_t)NCH * CHUNKF) + 15) & ~15ull;   // ~1 MB
    size_t bUC   = (size_t)NCH * 4;                          // 2 KB
    size_t bUL   = (size_t)NCH * CHUNKF * 4;                 // 4 MB
    size_t needFull = bHoff + bS1 + bUC + bUL;

    size_t bytesTf16 = (size_t)V * 4 * sizeof(__half);
    size_t bytesEf32 = (size_t)V * 4 * sizeof(float);

    if (ws_size >= needFull && NB <= NBMAX && CHUNKF <= CHMAX) {
        char* p = (char*)d_ws;
        unsigned int*  Hoff    = (unsigned int*)p;   p += bHoff;
        unsigned char* S1      = (unsigned char*)p;  p += bS1;
        int*           unstCnt = (int*)p;            p += bUC;
        int*           unstList = (int*)p;

        sort_kernel<<<NCH, 1024, 0, stream>>>(faces, Hoff, S1, unstCnt, unstList,
                                              F, V, NB, CHUNKF);
        countfinish_kernel<<<NB, 256, 0, stream>>>(mesh, cano, Hoff, S1,
                                                   unstCnt, unstList, faces,
                                                   out, V, NB, CHUNKF);
    } else if (ws_size >= bytesTf16 + bytesEf32) {
        __half* T = (__half*)d_ws;
        float*  E = (float*)((char*)d_ws + bytesTf16);
        (void)hipMemsetAsync(d_ws, 0, bytesTf16 + bytesEf32, stream);
        face_kernel_f16<<<(F + TB - 1) / TB, TB, 0, stream>>>(mesh, cano, faces, T, E, F, V);
        finish_kernel_f16<<<(V + TB - 1) / TB, TB, 0, stream>>>(T, E, out, V);
    } else {
        (void)hipMemsetAsync(out, 0, (size_t)V * 4 * sizeof(float), stream);
        face_kernel_direct<<<(F + TB - 1) / TB, TB, 0, stream>>>(mesh, cano, faces, out, F);
        norm_kernel<<<(V + TB - 1) / TB, TB, 0, stream>>>(out, V);
    }
}